// Round 1
// baseline (531.593 us; speedup 1.0000x reference)
//
#include <hip/hip_runtime.h>
#include <stdint.h>

typedef unsigned short u16;
typedef __attribute__((ext_vector_type(8))) short bf16x8;
typedef __attribute__((ext_vector_type(4))) float f32x4;

#define LSEQ 2048
#define BSZ  32
#define HDIM 512
#define PDIM 256
#define MR   (LSEQ*BSZ)

__device__ __forceinline__ u16 f2bf(float f) {
  union { float f; uint32_t u; } x; x.f = f;
  uint32_t r = x.u + 0x7FFFu + ((x.u >> 16) & 1u);
  return (u16)(r >> 16);
}
__device__ __forceinline__ float bf2f(u16 s) {
  union { uint32_t u; float f; } x; x.u = ((uint32_t)s) << 16; return x.f;
}
__device__ __forceinline__ void gload16(const void* gp, void* lp) {
  __builtin_amdgcn_global_load_lds((const __attribute__((address_space(1))) void*)gp,
                                   (__attribute__((address_space(3))) void*)lp, 16, 0, 0);
}

// ---------- prep1: Lam_bar and (Lam_bar-1)/Lam per p ----------
// lam layout: [0:256)=lbr [256:512)=lbi [512:768)=fre [768:1024)=fim
__global__ __launch_bounds__(256) void prep1_kernel(
    const float* __restrict__ Lre, const float* __restrict__ Lim,
    const float* __restrict__ lstep, float* __restrict__ lam)
{
  int p = threadIdx.x;
  float delta = expf(lstep[p]);
  float lr = Lre[p], li = Lim[p];
  float mag = expf(lr * delta);
  float ang = li * delta;
  float lbr = mag * cosf(ang);
  float lbi = mag * sinf(ang);
  lam[p] = lbr; lam[256 + p] = lbi;
  float nr = lbr - 1.f, ni = lbi;
  float inv = 1.f / (lr*lr + li*li);
  lam[512 + p] = (nr*lr + ni*li) * inv;   // (Lam_bar-1)*conj(Lam)/|Lam|^2
  lam[768 + p] = (ni*lr - nr*li) * inv;
}

// ---------- prep2: bf16 weight matrices ----------
// Btbu[512][512]: rows 0..255 = B_bar_re[p,:], rows 256..511 = B_bar_im[p,:]
// Ct[512][512]:   Ct[h][0:256)=2*C_re[h,:], [256:512)=-2*C_im[h,:]
// W1t/W2t[512][512]: W1t[j][h] = W1[h][j]
__global__ __launch_bounds__(256) void prep2_kernel(
  const float* __restrict__ Bre, const float* __restrict__ Bim,
  const float* __restrict__ Cre, const float* __restrict__ Cim,
  const float* __restrict__ W1, const float* __restrict__ W2,
  const float* __restrict__ lam,
  u16* __restrict__ Btbu, u16* __restrict__ Ct,
  u16* __restrict__ W1t, u16* __restrict__ W2t)
{
  int id = blockIdx.x * 256 + threadIdx.x;   // 0..262143
  int a = id >> 9, b = id & 511;
  if (id < PDIM * HDIM) {
    int p = a, h = b;
    float fre = lam[512 + p], fim = lam[768 + p];
    float br = Bre[p * HDIM + h], bim = Bim[p * HDIM + h];
    Btbu[(size_t)p * HDIM + h]        = f2bf(fre*br - fim*bim);
    Btbu[(size_t)(p+PDIM) * HDIM + h] = f2bf(fre*bim + fim*br);
  }
  {
    int h = a, c = b;
    float v = (c < PDIM) ? 2.f * Cre[h * PDIM + c] : -2.f * Cim[h * PDIM + (c - PDIM)];
    Ct[id]  = f2bf(v);
    W1t[id] = f2bf(W1[b * HDIM + a]);
    W2t[id] = f2bf(W2[b * HDIM + a]);
  }
}

// ---------- ln1: x f32 -> xn bf16 (one wave per row of 512) ----------
__global__ __launch_bounds__(256) void ln1_kernel(const float* __restrict__ x,
    const float* __restrict__ sc, const float* __restrict__ bi, u16* __restrict__ xn)
{
  const int row = blockIdx.x * 4 + (threadIdx.x >> 6);
  const int lane = threadIdx.x & 63;
  const size_t base = (size_t)row * HDIM + lane * 8;
  float4 a0 = *(const float4*)(x + base);
  float4 a1 = *(const float4*)(x + base + 4);
  float v[8] = {a0.x,a0.y,a0.z,a0.w,a1.x,a1.y,a1.z,a1.w};
  float s = 0.f, ss = 0.f;
  #pragma unroll
  for (int j = 0; j < 8; j++) { s += v[j]; ss += v[j]*v[j]; }
  #pragma unroll
  for (int o = 32; o; o >>= 1) { s += __shfl_xor(s, o); ss += __shfl_xor(ss, o); }
  float mean = s * (1.f / HDIM);
  float var  = ss * (1.f / HDIM) - mean * mean;
  float rstd = rsqrtf(var + 1e-6f);
  const int hb = lane * 8;
  bf16x8 r;
  #pragma unroll
  for (int j = 0; j < 8; j++) {
    float o = (v[j] - mean) * rstd * sc[hb + j] + bi[hb + j];
    r[j] = (short)f2bf(o);
  }
  *(bf16x8*)(xn + base) = r;
}

// ---------- 128x128 bf16 MFMA GEMM: C[M,N] = A[M,K] * Bt[N,K]^T ----------
__global__ __launch_bounds__(256) void gemm128_kernel(const u16* __restrict__ A,
    const u16* __restrict__ Bt, float* __restrict__ C, int N, int K)
{
  __shared__ u16 lA[128 * 32];
  __shared__ u16 lB[128 * 32];
  const int tid = threadIdx.x, lane = tid & 63, w = tid >> 6;
  const int wr = w >> 1, wc = w & 1;
  const int m0 = blockIdx.x * 128, n0 = blockIdx.y * 128;
  const int lr4 = lane >> 2, lc16 = (lane & 3) * 8;
  f32x4 zero = {0.f, 0.f, 0.f, 0.f};
  f32x4 acc[4][4];
  #pragma unroll
  for (int i = 0; i < 4; i++) {
    #pragma unroll
    for (int j = 0; j < 4; j++) acc[i][j] = zero;
  }
  const int nks = K >> 5;
  for (int ks = 0; ks < nks; ++ks) {
    const int kb = ks * 32;
    #pragma unroll
    for (int i = 0; i < 2; i++) {
      const int r0 = (w * 2 + i) * 16;
      gload16(A  + (size_t)(m0 + r0 + lr4) * K + kb + lc16, &lA[r0 * 32]);
      gload16(Bt + (size_t)(n0 + r0 + lr4) * K + kb + lc16, &lB[r0 * 32]);
    }
    __syncthreads();
    const int kk = (lane >> 4) * 8;
    bf16x8 af[4], bfv[4];
    #pragma unroll
    for (int f = 0; f < 4; f++) {
      af[f]  = *(const bf16x8*)&lA[(wr * 64 + f * 16 + (lane & 15)) * 32 + kk];
      bfv[f] = *(const bf16x8*)&lB[(wc * 64 + f * 16 + (lane & 15)) * 32 + kk];
    }
    #pragma unroll
    for (int i = 0; i < 4; i++) {
      #pragma unroll
      for (int j = 0; j < 4; j++)
        acc[i][j] = __builtin_amdgcn_mfma_f32_16x16x32_bf16(af[i], bfv[j], acc[i][j], 0, 0, 0);
    }
    __syncthreads();
  }
  #pragma unroll
  for (int i = 0; i < 4; i++) {
    const int row = m0 + wr * 64 + i * 16 + ((lane >> 4) << 2);
    #pragma unroll
    for (int j = 0; j < 4; j++) {
      const int col = n0 + wc * 64 + j * 16 + (lane & 15);
      #pragma unroll
      for (int r = 0; r < 4; r++) C[(size_t)(row + r) * N + col] = acc[i][j][r];
    }
  }
}

// ---------- scan pass A: per-chunk aggregates (64 chunks x 32 steps) ----------
__global__ __launch_bounds__(256) void scan_a_kernel(const float* __restrict__ Bu,
   const int* __restrict__ dg, const float* __restrict__ lam,
   float* __restrict__ aAr, float* __restrict__ aAi,
   float* __restrict__ abr, float* __restrict__ abi, float* __restrict__ ac)
{
  const int c = blockIdx.x >> 5;
  const int b = blockIdx.x & 31;
  const int p = threadIdx.x;
  const float lr = lam[p], li = lam[256 + p];
  float Ar = 1.f, Ai = 0.f, br = 0.f, bi = 0.f, ca = 0.f;
  for (int i = 0; i < 32; i++) {
    const int l = c * 32 + i;
    const size_t m = (size_t)(l * BSZ + b);
    float ur = Bu[m * HDIM + p];
    float ui = Bu[m * HDIM + PDIM + p];
    int dd = dg[l * BSZ + b];
    if (dd) { Ar = lr; Ai = li; br = ur; bi = ui; ca = 1.f; }
    else {
      float t1 = lr*Ar - li*Ai, t2 = lr*Ai + li*Ar;
      Ar = t1; Ai = t2;
      float t3 = lr*br - li*bi + ur, t4 = lr*bi + li*br + ui;
      br = t3; bi = t4;
    }
  }
  const int idx = blockIdx.x * 256 + p;
  aAr[idx] = Ar; aAi[idx] = Ai; abr[idx] = br; abi[idx] = bi; ac[idx] = ca;
}

// ---------- scan pass B: cross-chunk scan; emits chunk prefixes + hidden_out ----------
__global__ __launch_bounds__(256) void scan_b_kernel(
  const float* __restrict__ h0r, const float* __restrict__ h0i,
  const float* __restrict__ aAr, const float* __restrict__ aAi,
  const float* __restrict__ abr, const float* __restrict__ abi, const float* __restrict__ ac,
  float* __restrict__ prefr, float* __restrict__ prefi,
  float* __restrict__ hro, float* __restrict__ hio)
{
  const int t = blockIdx.x * 256 + threadIdx.x;   // = b*256 + p, 0..8191
  float hr = h0r[t], hi = h0i[t];
  for (int c = 0; c < 64; c++) {
    const int idx = c * 8192 + t;
    prefr[idx] = hr; prefi[idx] = hi;
    float Ar = aAr[idx], Ai = aAi[idx], br = abr[idx], bi = abi[idx], cc = ac[idx];
    float nr = Ar*hr - Ai*hi + br;
    float ni = Ar*hi + Ai*hr + bi;
    hr = (cc != 0.f) ? br : nr;
    hi = (cc != 0.f) ? bi : ni;
  }
  hro[t] = hr; hio[t] = hi;
}

// ---------- scan pass C: seeded replay, write states bf16 [m][0:256)=re [256:512)=im ----------
__global__ __launch_bounds__(256) void scan_c_kernel(const float* __restrict__ Bu,
   const int* __restrict__ dg, const float* __restrict__ lam,
   const float* __restrict__ prefr, const float* __restrict__ prefi,
   u16* __restrict__ St)
{
  const int c = blockIdx.x >> 5;
  const int b = blockIdx.x & 31;
  const int p = threadIdx.x;
  const float lr = lam[p], li = lam[256 + p];
  float hr = prefr[blockIdx.x * 256 + p];
  float hi = prefi[blockIdx.x * 256 + p];
  for (int i = 0; i < 32; i++) {
    const int l = c * 32 + i;
    const size_t m = (size_t)(l * BSZ + b);
    float ur = Bu[m * HDIM + p];
    float ui = Bu[m * HDIM + PDIM + p];
    int dd = dg[l * BSZ + b];
    if (dd) { hr = ur; hi = ui; }
    else {
      float t1 = lr*hr - li*hi + ur;
      float t2 = lr*hi + li*hr + ui;
      hr = t1; hi = t2;
    }
    St[m * HDIM + p]        = f2bf(hr);
    St[m * HDIM + PDIM + p] = f2bf(hi);
  }
}

// ---------- ln2 + D*xn + gelu; writes g bf16 in place over xn ----------
__global__ __launch_bounds__(256) void ln2_gelu_kernel(const float* __restrict__ Yg,
    u16* xg, const float* __restrict__ Dv,
    const float* __restrict__ sc, const float* __restrict__ bi)
{
  const int row = blockIdx.x * 4 + (threadIdx.x >> 6);
  const int lane = threadIdx.x & 63;
  const size_t base = (size_t)row * HDIM + lane * 8;
  float4 a0 = *(const float4*)(Yg + base);
  float4 a1 = *(const float4*)(Yg + base + 4);
  bf16x8 xv = *(const bf16x8*)(xg + base);
  const int hb = lane * 8;
  float4 d0 = *(const float4*)(Dv + hb);
  float4 d1 = *(const float4*)(Dv + hb + 4);
  float v[8] = {a0.x,a0.y,a0.z,a0.w,a1.x,a1.y,a1.z,a1.w};
  const float dd[8] = {d0.x,d0.y,d0.z,d0.w,d1.x,d1.y,d1.z,d1.w};
  #pragma unroll
  for (int j = 0; j < 8; j++) v[j] += dd[j] * bf2f((u16)xv[j]);
  float s = 0.f, ss = 0.f;
  #pragma unroll
  for (int j = 0; j < 8; j++) { s += v[j]; ss += v[j]*v[j]; }
  #pragma unroll
  for (int o = 32; o; o >>= 1) { s += __shfl_xor(s, o); ss += __shfl_xor(ss, o); }
  float mean = s * (1.f / HDIM);
  float var  = ss * (1.f / HDIM) - mean * mean;
  float rstd = rsqrtf(var + 1e-6f);
  bf16x8 r;
  #pragma unroll
  for (int j = 0; j < 8; j++) {
    float o = (v[j] - mean) * rstd * sc[hb + j] + bi[hb + j];
    float t = tanhf(0.7978845608f * (o + 0.044715f * o * o * o));
    float g = 0.5f * o * (1.f + t);
    r[j] = (short)f2bf(g);
  }
  *(bf16x8*)(xg + base) = r;
}

// ---------- fused MLP: out = x + (g@W1+b1)*sigmoid(g@W2+b2), tile 128x64 ----------
__global__ __launch_bounds__(256) void mlp_kernel(const u16* __restrict__ G,
  const u16* __restrict__ W1t, const u16* __restrict__ W2t,
  const float* __restrict__ b1, const float* __restrict__ b2,
  const float* __restrict__ X, float* __restrict__ Out)
{
  __shared__ u16 lA[128 * 32];
  __shared__ u16 lB1[64 * 32];
  __shared__ u16 lB2[64 * 32];
  const int tid = threadIdx.x, lane = tid & 63, w = tid >> 6;
  const int wr = w >> 1, wc = w & 1;
  const int m0 = blockIdx.x * 128, n0 = blockIdx.y * 64;
  const int lr4 = lane >> 2, lc16 = (lane & 3) * 8;
  f32x4 zero = {0.f, 0.f, 0.f, 0.f};
  f32x4 a1[4][2], a2[4][2];
  #pragma unroll
  for (int i = 0; i < 4; i++) {
    #pragma unroll
    for (int j = 0; j < 2; j++) { a1[i][j] = zero; a2[i][j] = zero; }
  }
  for (int ks = 0; ks < 16; ++ks) {
    const int kb = ks * 32;
    #pragma unroll
    for (int i = 0; i < 2; i++) {
      const int r0 = (w * 2 + i) * 16;
      gload16(G + (size_t)(m0 + r0 + lr4) * HDIM + kb + lc16, &lA[r0 * 32]);
    }
    {
      const int r0 = w * 16;
      gload16(W1t + (size_t)(n0 + r0 + lr4) * HDIM + kb + lc16, &lB1[r0 * 32]);
      gload16(W2t + (size_t)(n0 + r0 + lr4) * HDIM + kb + lc16, &lB2[r0 * 32]);
    }
    __syncthreads();
    const int kk = (lane >> 4) * 8;
    bf16x8 af[4], f1[2], f2v[2];
    #pragma unroll
    for (int f = 0; f < 4; f++) af[f] = *(const bf16x8*)&lA[(wr * 64 + f * 16 + (lane & 15)) * 32 + kk];
    #pragma unroll
    for (int j = 0; j < 2; j++) {
      f1[j]  = *(const bf16x8*)&lB1[(wc * 32 + j * 16 + (lane & 15)) * 32 + kk];
      f2v[j] = *(const bf16x8*)&lB2[(wc * 32 + j * 16 + (lane & 15)) * 32 + kk];
    }
    #pragma unroll
    for (int i = 0; i < 4; i++) {
      #pragma unroll
      for (int j = 0; j < 2; j++) {
        a1[i][j] = __builtin_amdgcn_mfma_f32_16x16x32_bf16(af[i], f1[j],  a1[i][j], 0, 0, 0);
        a2[i][j] = __builtin_amdgcn_mfma_f32_16x16x32_bf16(af[i], f2v[j], a2[i][j], 0, 0, 0);
      }
    }
    __syncthreads();
  }
  #pragma unroll
  for (int i = 0; i < 4; i++) {
    const int rowb = m0 + wr * 64 + i * 16 + ((lane >> 4) << 2);
    #pragma unroll
    for (int j = 0; j < 2; j++) {
      const int col = n0 + wc * 32 + j * 16 + (lane & 15);
      const float bb1 = b1[col], bb2 = b2[col];
      #pragma unroll
      for (int r = 0; r < 4; r++) {
        const size_t idx = (size_t)(rowb + r) * HDIM + col;
        float o1 = a1[i][j][r] + bb1;
        float o2 = a2[i][j][r] + bb2;
        float vv = o1 / (1.f + expf(-o2));
        Out[idx] = X[idx] + vv;
      }
    }
  }
}

extern "C" void kernel_launch(void* const* d_in, const int* in_sizes, int n_in,
                              void* d_out, int out_size, void* d_ws, size_t ws_size,
                              hipStream_t stream) {
  (void)in_sizes; (void)n_in; (void)out_size; (void)ws_size;
  const float* h0r = (const float*)d_in[0];
  const float* h0i = (const float*)d_in[1];
  const float* x   = (const float*)d_in[2];
  const float* Lre = (const float*)d_in[3];
  const float* Lim = (const float*)d_in[4];
  const float* Bre = (const float*)d_in[5];
  const float* Bim = (const float*)d_in[6];
  const float* Cre = (const float*)d_in[7];
  const float* Cim = (const float*)d_in[8];
  const float* Dv  = (const float*)d_in[9];
  const float* lst = (const float*)d_in[10];
  const float* nsc = (const float*)d_in[11];
  const float* nbi = (const float*)d_in[12];
  const float* W1  = (const float*)d_in[13];
  const float* b1  = (const float*)d_in[14];
  const float* W2  = (const float*)d_in[15];
  const float* b2  = (const float*)d_in[16];
  const int*   dg  = (const int*)d_in[17];

  // ws layout (total ~151 MB)
  char* ws = (char*)d_ws;
  u16* Btbu = (u16*)(ws);                       // 512KB
  u16* Ct   = (u16*)(ws + 524288);              // 512KB
  u16* W1t  = (u16*)(ws + 1048576);             // 512KB
  u16* W2t  = (u16*)(ws + 1572864);             // 512KB
  float* lam = (float*)(ws + 2097152);          // 4KB
  u16* xg   = (u16*)(ws + 2101248);             // 64MB  (xn, later g in place)
  u16* St   = (u16*)(ws + 2101248 + 67108864);  // 64MB  (states bf16)
  char* ag  = ws + 2101248 + 2 * 67108864;
  float* aAr = (float*)(ag);
  float* aAi = (float*)(ag + 2097152);
  float* abr = (float*)(ag + 2 * 2097152);
  float* abi = (float*)(ag + 3 * 2097152);
  float* ac  = (float*)(ag + 4 * 2097152);
  float* prr = (float*)(ag + 5 * 2097152);
  float* pri = (float*)(ag + 6 * 2097152);

  float* out = (float*)d_out;
  float* Bu  = out;                 // d_out head [0, 33554432) doubles as f32 scratch
  float* Yg  = out;                 // y-GEMM output reuses it after scan consumed Bu
  float* hro = out + 33554432;      // hidden_out.real
  float* hio = out + 33554432 + 8192;

  prep1_kernel<<<1, 256, 0, stream>>>(Lre, Lim, lst, lam);
  prep2_kernel<<<1024, 256, 0, stream>>>(Bre, Bim, Cre, Cim, W1, W2, lam, Btbu, Ct, W1t, W2t);
  ln1_kernel<<<16384, 256, 0, stream>>>(x, nsc, nbi, xg);
  gemm128_kernel<<<dim3(512, 4), 256, 0, stream>>>(xg, Btbu, Bu, 512, 512);
  scan_a_kernel<<<2048, 256, 0, stream>>>(Bu, dg, lam, aAr, aAi, abr, abi, ac);
  scan_b_kernel<<<32, 256, 0, stream>>>(h0r, h0i, aAr, aAi, abr, abi, ac, prr, pri, hro, hio);
  scan_c_kernel<<<2048, 256, 0, stream>>>(Bu, dg, lam, prr, pri, St);
  gemm128_kernel<<<dim3(512, 4), 256, 0, stream>>>(St, Ct, Yg, 512, 512);
  ln2_gelu_kernel<<<16384, 256, 0, stream>>>(Yg, xg, Dv, nsc, nbi);
  mlp_kernel<<<dim3(512, 8), 256, 0, stream>>>(xg, W1t, W2t, b1, b2, x, out);
}

// Round 2
// 439.907 us; speedup vs baseline: 1.2084x; 1.2084x over previous
//
#include <hip/hip_runtime.h>
#include <stdint.h>

typedef unsigned short u16;
typedef __attribute__((ext_vector_type(8))) short bf16x8;
typedef __attribute__((ext_vector_type(4))) float f32x4;

#define LSEQ 2048
#define BSZ  32
#define HDIM 512
#define PDIM 256

__device__ __forceinline__ u16 f2bf(float f) {
  union { float f; uint32_t u; } x; x.f = f;
  uint32_t r = x.u + 0x7FFFu + ((x.u >> 16) & 1u);
  return (u16)(r >> 16);
}
__device__ __forceinline__ float bf2f(u16 s) {
  union { uint32_t u; float f; } x; x.u = ((uint32_t)s) << 16; return x.f;
}
__device__ __forceinline__ void gload16(const void* gp, void* lp) {
  __builtin_amdgcn_global_load_lds((const __attribute__((address_space(1))) void*)gp,
                                   (__attribute__((address_space(3))) void*)lp, 16, 0, 0);
}

// ---------- prep1: Lam_bar and (Lam_bar-1)/Lam per p ----------
__global__ __launch_bounds__(256) void prep1_kernel(
    const float* __restrict__ Lre, const float* __restrict__ Lim,
    const float* __restrict__ lstep, float* __restrict__ lam)
{
  int p = threadIdx.x;
  float delta = expf(lstep[p]);
  float lr = Lre[p], li = Lim[p];
  float mag = expf(lr * delta);
  float ang = li * delta;
  float lbr = mag * cosf(ang);
  float lbi = mag * sinf(ang);
  lam[p] = lbr; lam[256 + p] = lbi;
  float nr = lbr - 1.f, ni = lbi;
  float inv = 1.f / (lr*lr + li*li);
  lam[512 + p] = (nr*lr + ni*li) * inv;
  lam[768 + p] = (ni*lr - nr*li) * inv;
}

// ---------- prep2: bf16 weight matrices ----------
__global__ __launch_bounds__(256) void prep2_kernel(
  const float* __restrict__ Bre, const float* __restrict__ Bim,
  const float* __restrict__ Cre, const float* __restrict__ Cim,
  const float* __restrict__ W1, const float* __restrict__ W2,
  const float* __restrict__ lam,
  u16* __restrict__ Btbu, u16* __restrict__ Ct,
  u16* __restrict__ W1t, u16* __restrict__ W2t)
{
  int id = blockIdx.x * 256 + threadIdx.x;
  int a = id >> 9, b = id & 511;
  if (id < PDIM * HDIM) {
    int p = a, h = b;
    float fre = lam[512 + p], fim = lam[768 + p];
    float br = Bre[p * HDIM + h], bim = Bim[p * HDIM + h];
    Btbu[(size_t)p * HDIM + h]        = f2bf(fre*br - fim*bim);
    Btbu[(size_t)(p+PDIM) * HDIM + h] = f2bf(fre*bim + fim*br);
  }
  {
    int h = a, c = b;
    float v = (c < PDIM) ? 2.f * Cre[h * PDIM + c] : -2.f * Cim[h * PDIM + (c - PDIM)];
    Ct[id]  = f2bf(v);
    W1t[id] = f2bf(W1[b * HDIM + a]);
    W2t[id] = f2bf(W2[b * HDIM + a]);
  }
}

// ---------- ln1 ----------
__global__ __launch_bounds__(256) void ln1_kernel(const float* __restrict__ x,
    const float* __restrict__ sc, const float* __restrict__ bi, u16* __restrict__ xn)
{
  const int row = blockIdx.x * 4 + (threadIdx.x >> 6);
  const int lane = threadIdx.x & 63;
  const size_t base = (size_t)row * HDIM + lane * 8;
  float4 a0 = *(const float4*)(x + base);
  float4 a1 = *(const float4*)(x + base + 4);
  float v[8] = {a0.x,a0.y,a0.z,a0.w,a1.x,a1.y,a1.z,a1.w};
  float s = 0.f, ss = 0.f;
  #pragma unroll
  for (int j = 0; j < 8; j++) { s += v[j]; ss += v[j]*v[j]; }
  #pragma unroll
  for (int o = 32; o; o >>= 1) { s += __shfl_xor(s, o); ss += __shfl_xor(ss, o); }
  float mean = s * (1.f / HDIM);
  float var  = ss * (1.f / HDIM) - mean * mean;
  float rstd = rsqrtf(var + 1e-6f);
  const int hb = lane * 8;
  bf16x8 r;
  #pragma unroll
  for (int j = 0; j < 8; j++) {
    float o = (v[j] - mean) * rstd * sc[hb + j] + bi[hb + j];
    r[j] = (short)f2bf(o);
  }
  *(bf16x8*)(xn + base) = r;
}

// ---------- Bu GEMM: Bu[m][512] bf16 = xn @ Btbu^T. BK=64, XOR-swizzled LDS ----------
__global__ __launch_bounds__(256) void gemm_bu_kernel(const u16* __restrict__ A,
    const u16* __restrict__ Bt, u16* __restrict__ C)
{
  __shared__ u16 lA[128 * 64];
  __shared__ u16 lB[128 * 64];
  const int tid = threadIdx.x, lane = tid & 63, w = tid >> 6;
  const int wr = w >> 1, wc = w & 1;
  const int m0 = blockIdx.x * 128, n0 = blockIdx.y * 128;
  const int srow = lane >> 3, slot = lane & 7;
  const int ksw = ((slot ^ srow) * 8);   // pre-swizzled source k-offset (u16)
  f32x4 zero = {0.f, 0.f, 0.f, 0.f};
  f32x4 acc[4][4];
  #pragma unroll
  for (int i = 0; i < 4; i++)
    #pragma unroll
    for (int j = 0; j < 4; j++) acc[i][j] = zero;

  for (int ks = 0; ks < 8; ++ks) {
    const int kb = ks * 64;
    #pragma unroll
    for (int i = 0; i < 4; i++) {
      const int rb = w * 32 + i * 8;
      gload16(A  + (size_t)(m0 + rb + srow) * HDIM + kb + ksw, &lA[rb * 64]);
      gload16(Bt + (size_t)(n0 + rb + srow) * HDIM + kb + ksw, &lB[rb * 64]);
    }
    __syncthreads();
    const int kk = (lane >> 4) * 8;
    bf16x8 af[4][2], bfv[4][2];
    #pragma unroll
    for (int f = 0; f < 4; f++) {
      const int ra = wr * 64 + f * 16 + (lane & 15);
      const int rb = wc * 64 + f * 16 + (lane & 15);
      const int sa = (ra & 7) << 3, sb = (rb & 7) << 3;
      af[f][0]  = *(const bf16x8*)&lA[ra * 64 + ((kk)      ^ sa)];
      af[f][1]  = *(const bf16x8*)&lA[ra * 64 + ((32 + kk) ^ sa)];
      bfv[f][0] = *(const bf16x8*)&lB[rb * 64 + ((kk)      ^ sb)];
      bfv[f][1] = *(const bf16x8*)&lB[rb * 64 + ((32 + kk) ^ sb)];
    }
    #pragma unroll
    for (int h = 0; h < 2; h++)
      #pragma unroll
      for (int i = 0; i < 4; i++)
        #pragma unroll
        for (int j = 0; j < 4; j++)
          acc[i][j] = __builtin_amdgcn_mfma_f32_16x16x32_bf16(af[i][h], bfv[j][h], acc[i][j], 0, 0, 0);
    __syncthreads();
  }
  #pragma unroll
  for (int i = 0; i < 4; i++) {
    const int row = m0 + wr * 64 + i * 16 + ((lane >> 4) << 2);
    #pragma unroll
    for (int j = 0; j < 4; j++) {
      const int col = n0 + wc * 64 + j * 16 + (lane & 15);
      #pragma unroll
      for (int r = 0; r < 4; r++) C[(size_t)(row + r) * HDIM + col] = f2bf(acc[i][j][r]);
    }
  }
}

// ---------- scan pass A (Bu bf16) ----------
__global__ __launch_bounds__(256) void scan_a_kernel(const u16* __restrict__ Bu,
   const int* __restrict__ dg, const float* __restrict__ lam,
   float* __restrict__ aAr, float* __restrict__ aAi,
   float* __restrict__ abr, float* __restrict__ abi, float* __restrict__ ac)
{
  const int c = blockIdx.x >> 5;
  const int b = blockIdx.x & 31;
  const int p = threadIdx.x;
  const float lr = lam[p], li = lam[256 + p];
  float Ar = 1.f, Ai = 0.f, br = 0.f, bi = 0.f, ca = 0.f;
  for (int i = 0; i < 32; i++) {
    const int l = c * 32 + i;
    const size_t m = (size_t)(l * BSZ + b);
    float ur = bf2f(Bu[m * HDIM + p]);
    float ui = bf2f(Bu[m * HDIM + PDIM + p]);
    int dd = dg[l * BSZ + b];
    if (dd) { Ar = lr; Ai = li; br = ur; bi = ui; ca = 1.f; }
    else {
      float t1 = lr*Ar - li*Ai, t2 = lr*Ai + li*Ar;
      Ar = t1; Ai = t2;
      float t3 = lr*br - li*bi + ur, t4 = lr*bi + li*br + ui;
      br = t3; bi = t4;
    }
  }
  const int idx = blockIdx.x * 256 + p;
  aAr[idx] = Ar; aAi[idx] = Ai; abr[idx] = br; abi[idx] = bi; ac[idx] = ca;
}

// ---------- scan pass B ----------
__global__ __launch_bounds__(256) void scan_b_kernel(
  const float* __restrict__ h0r, const float* __restrict__ h0i,
  const float* __restrict__ aAr, const float* __restrict__ aAi,
  const float* __restrict__ abr, const float* __restrict__ abi, const float* __restrict__ ac,
  float* __restrict__ prefr, float* __restrict__ prefi,
  float* __restrict__ hro, float* __restrict__ hio)
{
  const int t = blockIdx.x * 256 + threadIdx.x;
  float hr = h0r[t], hi = h0i[t];
  for (int c = 0; c < 64; c++) {
    const int idx = c * 8192 + t;
    prefr[idx] = hr; prefi[idx] = hi;
    float Ar = aAr[idx], Ai = aAi[idx], br = abr[idx], bi = abi[idx], cc = ac[idx];
    float nr = Ar*hr - Ai*hi + br;
    float ni = Ar*hi + Ai*hr + bi;
    hr = (cc != 0.f) ? br : nr;
    hi = (cc != 0.f) ? bi : ni;
  }
  hro[t] = hr; hio[t] = hi;
}

// ---------- scan pass C (Bu bf16 in, states bf16 out) ----------
__global__ __launch_bounds__(256) void scan_c_kernel(const u16* __restrict__ Bu,
   const int* __restrict__ dg, const float* __restrict__ lam,
   const float* __restrict__ prefr, const float* __restrict__ prefi,
   u16* __restrict__ St)
{
  const int c = blockIdx.x >> 5;
  const int b = blockIdx.x & 31;
  const int p = threadIdx.x;
  const float lr = lam[p], li = lam[256 + p];
  float hr = prefr[blockIdx.x * 256 + p];
  float hi = prefi[blockIdx.x * 256 + p];
  for (int i = 0; i < 32; i++) {
    const int l = c * 32 + i;
    const size_t m = (size_t)(l * BSZ + b);
    float ur = bf2f(Bu[m * HDIM + p]);
    float ui = bf2f(Bu[m * HDIM + PDIM + p]);
    int dd = dg[l * BSZ + b];
    if (dd) { hr = ur; hi = ui; }
    else {
      float t1 = lr*hr - li*hi + ur;
      float t2 = lr*hi + li*hr + ui;
      hr = t1; hi = t2;
    }
    St[m * HDIM + p]        = f2bf(hr);
    St[m * HDIM + PDIM + p] = f2bf(hi);
  }
}

// ---------- fused y-GEMM + D*xn + LN2 + gelu -> g bf16 (in place over xn) ----------
// block: 64 rows x full 512 cols, 8 waves (wave w owns cols [w*64, w*64+64))
__global__ __launch_bounds__(512) void ygln_kernel(const u16* __restrict__ St,
  const u16* __restrict__ Ct, u16* xg, const float* __restrict__ Dv,
  const float* __restrict__ sc, const float* __restrict__ bi)
{
  __shared__ u16 lA[64 * 32];    // 4KB
  __shared__ u16 lB[512 * 32];   // 32KB
  const int tid = threadIdx.x, lane = tid & 63, w = tid >> 6;
  const int m0 = blockIdx.x * 64;
  const int srow = lane >> 2, slot = lane & 3;
  const int ksw = ((slot ^ (srow & 3)) * 8);
  f32x4 zero = {0.f, 0.f, 0.f, 0.f};
  f32x4 acc[4][4];
  #pragma unroll
  for (int i = 0; i < 4; i++)
    #pragma unroll
    for (int j = 0; j < 4; j++) acc[i][j] = zero;

  for (int ks = 0; ks < 16; ++ks) {
    const int kb = ks * 32;
    if (w < 4) {  // stage lA: 64 rows, 4 instrs
      const int rb = w * 16;
      gload16(St + (size_t)(m0 + rb + srow) * HDIM + kb + ksw, &lA[rb * 32]);
    }
    #pragma unroll
    for (int i = 0; i < 4; i++) {  // stage lB: 512 rows, 8 waves x 4 instrs
      const int rb = w * 64 + i * 16;
      gload16(Ct + (size_t)(rb + srow) * HDIM + kb + ksw, &lB[rb * 32]);
    }
    __syncthreads();
    const int kk = (lane >> 4) * 8;
    bf16x8 af[4], bfv[4];
    #pragma unroll
    for (int f = 0; f < 4; f++) {
      const int ra = f * 16 + (lane & 15);
      const int rb = w * 64 + f * 16 + (lane & 15);
      af[f]  = *(const bf16x8*)&lA[ra * 32 + (kk ^ ((ra & 3) << 3))];
      bfv[f] = *(const bf16x8*)&lB[rb * 32 + (kk ^ ((rb & 3) << 3))];
    }
    #pragma unroll
    for (int i = 0; i < 4; i++)
      #pragma unroll
      for (int j = 0; j < 4; j++)
        acc[i][j] = __builtin_amdgcn_mfma_f32_16x16x32_bf16(af[i], bfv[j], acc[i][j], 0, 0, 0);
    __syncthreads();
  }

  // epilogue: v = acc + D*xn, then LN over full row (cross-wave), gelu, store bf16
  const int g = lane >> 4, l4 = lane & 15;
  float dcol[4], scol[4], bcol[4];
  #pragma unroll
  for (int j = 0; j < 4; j++) {
    const int col = w * 64 + j * 16 + l4;
    dcol[j] = Dv[col]; scol[j] = sc[col]; bcol[j] = bi[col];
  }
  #pragma unroll
  for (int i = 0; i < 4; i++)
    #pragma unroll
    for (int j = 0; j < 4; j++) {
      const int col = w * 64 + j * 16 + l4;
      #pragma unroll
      for (int r = 0; r < 4; r++) {
        const int row = i * 16 + g * 4 + r;
        acc[i][j][r] += dcol[j] * bf2f(xg[(size_t)(m0 + row) * HDIM + col]);
      }
    }
  float* sred = (float*)lB;  // reuse: need 1024+128 floats
  #pragma unroll
  for (int i = 0; i < 4; i++)
    #pragma unroll
    for (int r = 0; r < 4; r++) {
      float s = acc[i][0][r] + acc[i][1][r] + acc[i][2][r] + acc[i][3][r];
      float q = acc[i][0][r]*acc[i][0][r] + acc[i][1][r]*acc[i][1][r]
              + acc[i][2][r]*acc[i][2][r] + acc[i][3][r]*acc[i][3][r];
      #pragma unroll
      for (int o = 1; o < 16; o <<= 1) { s += __shfl_xor(s, o); q += __shfl_xor(q, o); }
      if (l4 == 0) {
        const int row = i * 16 + g * 4 + r;
        sred[row * 8 + w] = s; sred[512 + row * 8 + w] = q;
      }
    }
  __syncthreads();
  if (tid < 64) {
    float s = 0.f, q = 0.f;
    #pragma unroll
    for (int wv = 0; wv < 8; wv++) { s += sred[tid * 8 + wv]; q += sred[512 + tid * 8 + wv]; }
    float mean = s * (1.f / HDIM);
    float var  = q * (1.f / HDIM) - mean * mean;
    sred[1024 + tid] = mean;
    sred[1088 + tid] = rsqrtf(var + 1e-6f);
  }
  __syncthreads();
  #pragma unroll
  for (int i = 0; i < 4; i++)
    #pragma unroll
    for (int r = 0; r < 4; r++) {
      const int row = i * 16 + g * 4 + r;
      const float mean = sred[1024 + row], rstd = sred[1088 + row];
      #pragma unroll
      for (int j = 0; j < 4; j++) {
        const int col = w * 64 + j * 16 + l4;
        float o = (acc[i][j][r] - mean) * rstd * scol[j] + bcol[j];
        float t = tanhf(0.7978845608f * (o + 0.044715f * o * o * o));
        float gl = 0.5f * o * (1.f + t);
        xg[(size_t)(m0 + row) * HDIM + col] = f2bf(gl);
      }
    }
}

// ---------- fused MLP v2: BK=64, XOR-swizzled, tile 128x64 ----------
__global__ __launch_bounds__(256) void mlp_kernel(const u16* __restrict__ G,
  const u16* __restrict__ W1t, const u16* __restrict__ W2t,
  const float* __restrict__ b1, const float* __restrict__ b2,
  const float* __restrict__ X, float* __restrict__ Out)
{
  __shared__ u16 lG[128 * 64];   // 16KB
  __shared__ u16 lW1[64 * 64];   // 8KB
  __shared__ u16 lW2[64 * 64];   // 8KB
  const int tid = threadIdx.x, lane = tid & 63, w = tid >> 6;
  const int wr = w >> 1, wc = w & 1;
  const int m0 = blockIdx.x * 128, n0 = blockIdx.y * 64;
  const int srow = lane >> 3, slot = lane & 7;
  const int ksw = ((slot ^ srow) * 8);
  f32x4 zero = {0.f, 0.f, 0.f, 0.f};
  f32x4 a1[4][2], a2[4][2];
  #pragma unroll
  for (int i = 0; i < 4; i++)
    #pragma unroll
    for (int j = 0; j < 2; j++) { a1[i][j] = zero; a2[i][j] = zero; }

  for (int ks = 0; ks < 8; ++ks) {
    const int kb = ks * 64;
    #pragma unroll
    for (int i = 0; i < 4; i++) {
      const int rb = w * 32 + i * 8;
      gload16(G + (size_t)(m0 + rb + srow) * HDIM + kb + ksw, &lG[rb * 64]);
    }
    #pragma unroll
    for (int i = 0; i < 2; i++) {
      const int rb = w * 16 + i * 8;
      gload16(W1t + (size_t)(n0 + rb + srow) * HDIM + kb + ksw, &lW1[rb * 64]);
      gload16(W2t + (size_t)(n0 + rb + srow) * HDIM + kb + ksw, &lW2[rb * 64]);
    }
    __syncthreads();
    const int kk = (lane >> 4) * 8;
    bf16x8 af[4][2], f1[2][2], f2v[2][2];
    #pragma unroll
    for (int f = 0; f < 4; f++) {
      const int ra = wr * 64 + f * 16 + (lane & 15);
      const int sa = (ra & 7) << 3;
      af[f][0] = *(const bf16x8*)&lG[ra * 64 + ((kk)      ^ sa)];
      af[f][1] = *(const bf16x8*)&lG[ra * 64 + ((32 + kk) ^ sa)];
    }
    #pragma unroll
    for (int j = 0; j < 2; j++) {
      const int rb = wc * 32 + j * 16 + (lane & 15);
      const int sb = (rb & 7) << 3;
      f1[j][0]  = *(const bf16x8*)&lW1[rb * 64 + ((kk)      ^ sb)];
      f1[j][1]  = *(const bf16x8*)&lW1[rb * 64 + ((32 + kk) ^ sb)];
      f2v[j][0] = *(const bf16x8*)&lW2[rb * 64 + ((kk)      ^ sb)];
      f2v[j][1] = *(const bf16x8*)&lW2[rb * 64 + ((32 + kk) ^ sb)];
    }
    #pragma unroll
    for (int h = 0; h < 2; h++)
      #pragma unroll
      for (int i = 0; i < 4; i++)
        #pragma unroll
        for (int j = 0; j < 2; j++) {
          a1[i][j] = __builtin_amdgcn_mfma_f32_16x16x32_bf16(af[i][h], f1[j][h],  a1[i][j], 0, 0, 0);
          a2[i][j] = __builtin_amdgcn_mfma_f32_16x16x32_bf16(af[i][h], f2v[j][h], a2[i][j], 0, 0, 0);
        }
    __syncthreads();
  }
  #pragma unroll
  for (int i = 0; i < 4; i++) {
    const int rowb = m0 + wr * 64 + i * 16 + ((lane >> 4) << 2);
    #pragma unroll
    for (int j = 0; j < 2; j++) {
      const int col = n0 + wc * 32 + j * 16 + (lane & 15);
      const float bb1 = b1[col], bb2 = b2[col];
      #pragma unroll
      for (int r = 0; r < 4; r++) {
        const size_t idx = (size_t)(rowb + r) * HDIM + col;
        float o1 = a1[i][j][r] + bb1;
        float o2 = a2[i][j][r] + bb2;
        float vv = o1 / (1.f + expf(-o2));
        Out[idx] = X[idx] + vv;
      }
    }
  }
}

extern "C" void kernel_launch(void* const* d_in, const int* in_sizes, int n_in,
                              void* d_out, int out_size, void* d_ws, size_t ws_size,
                              hipStream_t stream) {
  (void)in_sizes; (void)n_in; (void)out_size; (void)ws_size;
  const float* h0r = (const float*)d_in[0];
  const float* h0i = (const float*)d_in[1];
  const float* x   = (const float*)d_in[2];
  const float* Lre = (const float*)d_in[3];
  const float* Lim = (const float*)d_in[4];
  const float* Bre = (const float*)d_in[5];
  const float* Bim = (const float*)d_in[6];
  const float* Cre = (const float*)d_in[7];
  const float* Cim = (const float*)d_in[8];
  const float* Dv  = (const float*)d_in[9];
  const float* lst = (const float*)d_in[10];
  const float* nsc = (const float*)d_in[11];
  const float* nbi = (const float*)d_in[12];
  const float* W1  = (const float*)d_in[13];
  const float* b1  = (const float*)d_in[14];
  const float* W2  = (const float*)d_in[15];
  const float* b2  = (const float*)d_in[16];
  const int*   dg  = (const int*)d_in[17];

  char* ws = (char*)d_ws;
  u16* Btbu = (u16*)(ws);
  u16* Ct   = (u16*)(ws + 524288);
  u16* W1t  = (u16*)(ws + 1048576);
  u16* W2t  = (u16*)(ws + 1572864);
  float* lam = (float*)(ws + 2097152);
  u16* xg   = (u16*)(ws + 2101248);             // 64MB (xn, later g in place)
  u16* St   = (u16*)(ws + 2101248 + 67108864);  // 64MB (states bf16)
  char* ag  = ws + 2101248 + 2 * 67108864;
  float* aAr = (float*)(ag);
  float* aAi = (float*)(ag + 2097152);
  float* abr = (float*)(ag + 2 * 2097152);
  float* abi = (float*)(ag + 3 * 2097152);
  float* ac  = (float*)(ag + 4 * 2097152);
  float* prr = (float*)(ag + 5 * 2097152);
  float* pri = (float*)(ag + 6 * 2097152);

  float* out = (float*)d_out;
  u16* Bu16  = (u16*)d_out;         // head of d_out doubles as bf16 Bu scratch
  float* hro = out + 33554432;
  float* hio = out + 33554432 + 8192;

  prep1_kernel<<<1, 256, 0, stream>>>(Lre, Lim, lst, lam);
  prep2_kernel<<<1024, 256, 0, stream>>>(Bre, Bim, Cre, Cim, W1, W2, lam, Btbu, Ct, W1t, W2t);
  ln1_kernel<<<16384, 256, 0, stream>>>(x, nsc, nbi, xg);
  gemm_bu_kernel<<<dim3(512, 4), 256, 0, stream>>>(xg, Btbu, Bu16);
  scan_a_kernel<<<2048, 256, 0, stream>>>(Bu16, dg, lam, aAr, aAi, abr, abi, ac);
  scan_b_kernel<<<32, 256, 0, stream>>>(h0r, h0i, aAr, aAi, abr, abi, ac, prr, pri, hro, hio);
  scan_c_kernel<<<2048, 256, 0, stream>>>(Bu16, dg, lam, prr, pri, St);
  ygln_kernel<<<1024, 512, 0, stream>>>(St, Ct, xg, Dv, nsc, nbi);
  mlp_kernel<<<dim3(512, 8), 256, 0, stream>>>(xg, W1t, W2t, b1, b2, x, out);
}